// Round 1
// baseline (759.238 us; speedup 1.0000x reference)
//
#include <hip/hip_runtime.h>

#define NN 100000   // N_NODES
#define F 64        // feature dim (= hidden dim)

// ---------------------------------------------------------------------------
// deg/dis: deg[i] = indeg(i); dis[i] = rsqrt(deg+1)  (self-loop folded in +1)
// ---------------------------------------------------------------------------
__global__ __launch_bounds__(256) void zero_kernel(float* p, int n) {
    int i = blockIdx.x * 256 + threadIdx.x;
    if (i < n) p[i] = 0.0f;
}

__global__ __launch_bounds__(256) void deg_kernel(const int* __restrict__ dst, int E,
                                                  float* __restrict__ deg) {
    int stride = gridDim.x * 256;
    for (int e = blockIdx.x * 256 + threadIdx.x; e < E; e += stride)
        atomicAdd(&deg[dst[e]], 1.0f);
}

__global__ __launch_bounds__(256) void rsqrt_kernel(float* p, int n) {
    int i = blockIdx.x * 256 + threadIdx.x;
    if (i < n) p[i] = rsqrtf(p[i] + 1.0f);   // +1 = self-loop; always > 0
}

// ---------------------------------------------------------------------------
// xs = (X @ W) * dis[row]; written to BOTH A (gather source) and Bm (accumulator
// init = self-loop term). 16 rows/block, 256 threads, 4 outputs/thread.
// wl[k][col]: 64 lanes -> 2-way bank alias (free). xl[r][k]: wave-broadcast.
// ---------------------------------------------------------------------------
__global__ __launch_bounds__(256) void gemm_scale(const float* __restrict__ X,
                                                  const float* __restrict__ W,
                                                  const float* __restrict__ dis,
                                                  float* __restrict__ A,
                                                  float* __restrict__ Bm) {
    __shared__ float wl[64][64];
    __shared__ float xl[16][64];
    int tid = threadIdx.x;
    for (int t = tid; t < 64 * 64; t += 256) wl[t >> 6][t & 63] = W[t];
    size_t base = (size_t)blockIdx.x * 16 * F;
    for (int t = tid; t < 16 * 64; t += 256) xl[t >> 6][t & 63] = X[base + t];
    __syncthreads();

    int col = tid & 63;
    int w   = tid >> 6;          // wave id -> rows w*4 .. w*4+3
    float a0 = 0.f, a1 = 0.f, a2 = 0.f, a3 = 0.f;
#pragma unroll
    for (int k = 0; k < 64; ++k) {
        float wk = wl[k][col];
        a0 = fmaf(xl[w * 4 + 0][k], wk, a0);
        a1 = fmaf(xl[w * 4 + 1][k], wk, a1);
        a2 = fmaf(xl[w * 4 + 2][k], wk, a2);
        a3 = fmaf(xl[w * 4 + 3][k], wk, a3);
    }
    int row = blockIdx.x * 16 + w * 4;
    float acc[4] = {a0, a1, a2, a3};
#pragma unroll
    for (int q = 0; q < 4; ++q) {
        float v = acc[q] * dis[row + q];
        size_t idx = (size_t)(row + q) * F + col;
        A[idx]  = v;
        Bm[idx] = v;
    }
}

// ---------------------------------------------------------------------------
// One wave per edge: lane f does acc[dst][f] += xs[src][f]. No multiplies.
// 256 B coalesced gather + 64 coalesced fp32 atomics per edge.
// ---------------------------------------------------------------------------
__global__ __launch_bounds__(256) void scatter_kernel(const int* __restrict__ src,
                                                      const int* __restrict__ dst,
                                                      int E,
                                                      const float* __restrict__ A,
                                                      float* __restrict__ Bm) {
    int lane = threadIdx.x & 63;
    int wave = blockIdx.x * 4 + (threadIdx.x >> 6);
    int nw   = gridDim.x * 4;
    for (int e = wave; e < E; e += nw) {
        int s = src[e];
        int d = dst[e];
        atomicAdd(&Bm[(size_t)d * F + lane], A[(size_t)s * F + lane]);
    }
}

// ---------------------------------------------------------------------------
// out[i][j] = (relu?)( b[j] + dis[i] * acc[i][j] )
// ---------------------------------------------------------------------------
__global__ __launch_bounds__(256) void finalize_kernel(const float* __restrict__ Bm,
                                                       const float* __restrict__ dis,
                                                       const float* __restrict__ bias,
                                                       float* __restrict__ out,
                                                       int do_relu) {
    int idx = blockIdx.x * 256 + threadIdx.x;
    if (idx < NN * F) {
        int i = idx >> 6, j = idx & 63;
        float v = fmaf(dis[i], Bm[idx], bias[j]);
        if (do_relu) v = fmaxf(v, 0.0f);
        out[idx] = v;
    }
}

extern "C" void kernel_launch(void* const* d_in, const int* in_sizes, int n_in,
                              void* d_out, int out_size, void* d_ws, size_t ws_size,
                              hipStream_t stream) {
    const float* x  = (const float*)d_in[0];
    const int*   ei = (const int*)d_in[1];   // [2,E] flat: src = ei[0:E], dst = ei[E:2E]
    const float* W1 = (const float*)d_in[2];
    const float* b1 = (const float*)d_in[3];
    const float* W2 = (const float*)d_in[4];
    const float* b2 = (const float*)d_in[5];
    float* out = (float*)d_out;
    int E = in_sizes[1] / 2;
    const int* src = ei;
    const int* dst = ei + E;

    // workspace layout: dis (N floats, 1 MB-aligned slab) | A (N*64) | Bm (N*64)
    char* ws = (char*)d_ws;
    float* dis = (float*)ws;
    float* A   = (float*)(ws + (1 << 20));
    float* Bm  = A + (size_t)NN * F;

    const int nodeBlocks = (NN + 255) / 256;

    // deg -> dis (in-place), once — shared by both layers
    zero_kernel<<<nodeBlocks, 256, 0, stream>>>(dis, NN);
    deg_kernel<<<2048, 256, 0, stream>>>(dst, E, dis);
    rsqrt_kernel<<<nodeBlocks, 256, 0, stream>>>(dis, NN);

    // ---- layer 1 ----
    gemm_scale<<<NN / 16, 256, 0, stream>>>(x, W1, dis, A, Bm);
    scatter_kernel<<<4096, 256, 0, stream>>>(src, dst, E, A, Bm);
    finalize_kernel<<<(NN * F + 255) / 256, 256, 0, stream>>>(Bm, dis, b1, out, 1); // h -> d_out

    // ---- layer 2 (reads h from d_out, overwrites d_out at the end) ----
    gemm_scale<<<NN / 16, 256, 0, stream>>>(out, W2, dis, A, Bm);
    scatter_kernel<<<4096, 256, 0, stream>>>(src, dst, E, A, Bm);
    finalize_kernel<<<(NN * F + 255) / 256, 256, 0, stream>>>(Bm, dis, b2, out, 0);
}

// Round 2
// 389.622 us; speedup vs baseline: 1.9487x; 1.9487x over previous
//
#include <hip/hip_runtime.h>

#define NN 100000   // N_NODES
#define F  64       // feature dim (= hidden dim)

// ---------------- workspace layout (element offsets, 4 B each) --------------
#define O_CNT     0          // int[100000]   in-degree histogram
#define O_INCL    100352     // int[100000]   per-block inclusive scan
#define O_BSUM    200704     // int[391]      block sums
#define O_BOFF    201216     // int[391]      exclusive block offsets
#define O_ROWPTR  201728     // int[100001]   CSR row pointers (by dst)
#define O_CURSOR  302080     // int[100000]   binning cursors
#define O_DIS     402432     // float[100000] rsqrt(deg+1)
#define O_SRT     502784     // int[E]        sorted src indices
#define O_A       1753088    // float[100000*64] xs = dis[i]*(X@W)[i]  (16B-aligned)

// ---------------------------------------------------------------------------
__global__ __launch_bounds__(256) void zero_int(int* p, int n) {
    int i = blockIdx.x * 256 + threadIdx.x;
    if (i < n) p[i] = 0;
}

__global__ __launch_bounds__(256) void hist_kernel(const int* __restrict__ dst, int E,
                                                   int* __restrict__ cnt) {
    int stride = gridDim.x * 256;
    for (int e = blockIdx.x * 256 + threadIdx.x; e < E; e += stride)
        atomicAdd(&cnt[dst[e]], 1);
}

// ---- 2-level exclusive scan of cnt[0..n) -> row_ptr, cursor; also dis ------
__global__ __launch_bounds__(256) void scan1(const int* __restrict__ cnt,
                                             int* __restrict__ incl,
                                             int* __restrict__ bsum, int n) {
    __shared__ int s[256];
    int i = blockIdx.x * 256 + threadIdx.x;
    int v = (i < n) ? cnt[i] : 0;
    s[threadIdx.x] = v;
    __syncthreads();
    for (int off = 1; off < 256; off <<= 1) {
        int t = (threadIdx.x >= off) ? s[threadIdx.x - off] : 0;
        __syncthreads();
        s[threadIdx.x] += t;
        __syncthreads();
    }
    if (i < n) incl[i] = s[threadIdx.x];
    if (threadIdx.x == 255) bsum[blockIdx.x] = s[255];
}

__global__ __launch_bounds__(512) void scan2(const int* __restrict__ bsum,
                                             int* __restrict__ boff, int nb) {
    __shared__ int s[512];
    int t = threadIdx.x;
    int v = (t < nb) ? bsum[t] : 0;
    s[t] = v;
    __syncthreads();
    for (int off = 1; off < 512; off <<= 1) {
        int u = (t >= off) ? s[t - off] : 0;
        __syncthreads();
        s[t] += u;
        __syncthreads();
    }
    if (t < nb) boff[t] = s[t] - v;   // exclusive
}

__global__ __launch_bounds__(256) void scan3(const int* __restrict__ cnt,
                                             const int* __restrict__ incl,
                                             const int* __restrict__ boff,
                                             int* __restrict__ row_ptr,
                                             int* __restrict__ cursor,
                                             float* __restrict__ dis,
                                             int n, int E) {
    int i = blockIdx.x * 256 + threadIdx.x;
    if (i < n) {
        int c = cnt[i];
        int r = boff[i >> 8] + (incl[i] - c);   // exclusive scan value
        row_ptr[i] = r;
        cursor[i]  = r;
        dis[i] = rsqrtf((float)c + 1.0f);       // +1 = self-loop
        if (i == 0) row_ptr[n] = E;
    }
}

__global__ __launch_bounds__(256) void bin_kernel(const int* __restrict__ src,
                                                  const int* __restrict__ dst, int E,
                                                  int* __restrict__ cursor,
                                                  int* __restrict__ srt) {
    int stride = gridDim.x * 256;
    for (int e = blockIdx.x * 256 + threadIdx.x; e < E; e += stride) {
        int p = atomicAdd(&cursor[dst[e]], 1);
        srt[p] = src[e];
    }
}

// ---------------------------------------------------------------------------
// A = (X @ W) * dis[row].  16 rows/block, 256 threads, 4 outputs/thread.
// ---------------------------------------------------------------------------
__global__ __launch_bounds__(256) void gemm_scale(const float* __restrict__ X,
                                                  const float* __restrict__ W,
                                                  const float* __restrict__ dis,
                                                  float* __restrict__ A) {
    __shared__ float wl[64][64];
    __shared__ float xl[16][64];
    int tid = threadIdx.x;
    for (int t = tid; t < 64 * 64; t += 256) wl[t >> 6][t & 63] = W[t];
    size_t base = (size_t)blockIdx.x * 16 * F;
    for (int t = tid; t < 16 * 64; t += 256) xl[t >> 6][t & 63] = X[base + t];
    __syncthreads();

    int col = tid & 63;
    int w   = tid >> 6;
    float a0 = 0.f, a1 = 0.f, a2 = 0.f, a3 = 0.f;
#pragma unroll
    for (int k = 0; k < 64; ++k) {
        float wk = wl[k][col];
        a0 = fmaf(xl[w * 4 + 0][k], wk, a0);
        a1 = fmaf(xl[w * 4 + 1][k], wk, a1);
        a2 = fmaf(xl[w * 4 + 2][k], wk, a2);
        a3 = fmaf(xl[w * 4 + 3][k], wk, a3);
    }
    int row = blockIdx.x * 16 + w * 4;
    float acc[4] = {a0, a1, a2, a3};
#pragma unroll
    for (int q = 0; q < 4; ++q)
        A[(size_t)(row + q) * F + col] = acc[q] * dis[row + q];
}

// ---------------------------------------------------------------------------
// Gather aggregation + fused finalize. 16 lanes per node (float4 per lane),
// 16 nodes per 256-thread block. acc seeded with self-loop term A[node].
// out[i] = (relu?)( b + dis[i] * (A[i] + sum_{e: dst=i} A[src[e]]) )
// ---------------------------------------------------------------------------
__global__ __launch_bounds__(256) void agg_kernel(const float4* __restrict__ A4,
                                                  const int* __restrict__ row_ptr,
                                                  const int* __restrict__ srt,
                                                  const float* __restrict__ dis,
                                                  const float* __restrict__ bias,
                                                  float4* __restrict__ out,
                                                  int do_relu) {
    int sub  = threadIdx.x & 15;                    // feature group: 4 floats
    int node = blockIdx.x * 16 + (threadIdx.x >> 4);
    int beg = row_ptr[node], end = row_ptr[node + 1];
    float4 acc = A4[(size_t)node * 16 + sub];       // self-loop
    int j = beg;
    for (; j + 2 <= end; j += 2) {                  // 2-wide for ILP
        int s0 = srt[j], s1 = srt[j + 1];
        float4 v0 = A4[(size_t)s0 * 16 + sub];
        float4 v1 = A4[(size_t)s1 * 16 + sub];
        acc.x += v0.x + v1.x;
        acc.y += v0.y + v1.y;
        acc.z += v0.z + v1.z;
        acc.w += v0.w + v1.w;
    }
    if (j < end) {
        float4 v0 = A4[(size_t)srt[j] * 16 + sub];
        acc.x += v0.x; acc.y += v0.y; acc.z += v0.z; acc.w += v0.w;
    }
    float dv = dis[node];
    float4 b = ((const float4*)bias)[sub];
    float4 o;
    o.x = fmaf(dv, acc.x, b.x);
    o.y = fmaf(dv, acc.y, b.y);
    o.z = fmaf(dv, acc.z, b.z);
    o.w = fmaf(dv, acc.w, b.w);
    if (do_relu) {
        o.x = fmaxf(o.x, 0.f); o.y = fmaxf(o.y, 0.f);
        o.z = fmaxf(o.z, 0.f); o.w = fmaxf(o.w, 0.f);
    }
    out[(size_t)node * 16 + sub] = o;
}

extern "C" void kernel_launch(void* const* d_in, const int* in_sizes, int n_in,
                              void* d_out, int out_size, void* d_ws, size_t ws_size,
                              hipStream_t stream) {
    const float* x  = (const float*)d_in[0];
    const int*   ei = (const int*)d_in[1];   // [2,E] flat: src = ei[0:E], dst = ei[E:2E]
    const float* W1 = (const float*)d_in[2];
    const float* b1 = (const float*)d_in[3];
    const float* W2 = (const float*)d_in[4];
    const float* b2 = (const float*)d_in[5];
    float* out = (float*)d_out;
    int E = in_sizes[1] / 2;
    const int* src = ei;
    const int* dst = ei + E;

    int*   ws_i     = (int*)d_ws;
    float* ws_f     = (float*)d_ws;
    int*   cnt      = ws_i + O_CNT;
    int*   incl     = ws_i + O_INCL;
    int*   bsum     = ws_i + O_BSUM;
    int*   boff     = ws_i + O_BOFF;
    int*   row_ptr  = ws_i + O_ROWPTR;
    int*   cursor   = ws_i + O_CURSOR;
    float* dis      = ws_f + O_DIS;
    int*   srt      = ws_i + O_SRT;
    float* A        = ws_f + O_A;

    const int nodeBlocks = (NN + 255) / 256;   // 391

    // ---- CSR build (once; shared by both layers) ----
    zero_int<<<nodeBlocks, 256, 0, stream>>>(cnt, NN);
    hist_kernel<<<2048, 256, 0, stream>>>(dst, E, cnt);
    scan1<<<nodeBlocks, 256, 0, stream>>>(cnt, incl, bsum, NN);
    scan2<<<1, 512, 0, stream>>>(bsum, boff, nodeBlocks);
    scan3<<<nodeBlocks, 256, 0, stream>>>(cnt, incl, boff, row_ptr, cursor, dis, NN, E);
    bin_kernel<<<2048, 256, 0, stream>>>(src, dst, E, cursor, srt);

    // ---- layer 1 ----
    gemm_scale<<<NN / 16, 256, 0, stream>>>(x, W1, dis, A);
    agg_kernel<<<NN / 16, 256, 0, stream>>>((const float4*)A, row_ptr, srt, dis, b1,
                                            (float4*)out, 1);
    // ---- layer 2 (reads h from d_out, overwrites d_out) ----
    gemm_scale<<<NN / 16, 256, 0, stream>>>(out, W2, dis, A);
    agg_kernel<<<NN / 16, 256, 0, stream>>>((const float4*)A, row_ptr, srt, dis, b2,
                                            (float4*)out, 0);
}